// Round 1
// baseline (224.080 us; speedup 1.0000x reference)
//
#include <hip/hip_runtime.h>

typedef __bf16 bf16x8 __attribute__((ext_vector_type(8)));
typedef float f32x4 __attribute__((ext_vector_type(4)));
typedef unsigned short u16;
typedef unsigned int u32;
typedef u16 u16x8 __attribute__((ext_vector_type(8)));
typedef u16 u16x4 __attribute__((ext_vector_type(4)));

#define L2ALPHA (-0.014499569f)   // log2(0.99)

static __device__ __forceinline__ u16 f2bf(float f) {
    u32 u = __builtin_bit_cast(u32, f);
    u32 r = (u + 0x7FFFu + ((u >> 16) & 1u)) >> 16;
    return (u16)r;
}

// ---------------------------------------------------------------------------
// Projection: qkv = x @ Wqkv + bqkv, split to q (scaled by 1/16), k, v (bf16)
// grid (6, 256), block 256.  BM=128, BN=128, BK=32, K=256.
// ---------------------------------------------------------------------------
__global__ __launch_bounds__(256, 2) void proj_kernel(
        const float* __restrict__ x, const float* __restrict__ Wq,
        const float* __restrict__ bias,
        u16* __restrict__ qb, u16* __restrict__ kb, u16* __restrict__ vb)
{
    // Bs: [kq 0..31][col 0..127][j 0..7]  (B^T-style: lane n reads 8 consecutive k)
    __shared__ __align__(16) u16 Bs[32 * 128 * 8];
    // As: [quarter 0..3][row 0..127][j 0..7]
    __shared__ __align__(16) u16 As[4 * 128 * 8];

    const int tid = threadIdx.x;
    const int lane = tid & 63;
    const int w = tid >> 6;
    const int nb = blockIdx.x;           // 0..5
    const int mb = blockIdx.y;           // 0..255
    const int m0 = mb * 128, n0 = nb * 128;
    const int wr = (w & 1) * 64, wc = (w >> 1) * 64;
    const int m = lane & 15, quad = lane >> 4;

    // stage whole B panel (256 x 128) once
    #pragma unroll
    for (int s = 0; s < 32; ++s) {
        int c = tid + 256 * s;           // 0..8191
        int k = c >> 5, part = c & 31;
        const float4 v4 = *(const float4*)(Wq + k * 768 + n0 + part * 4);
        int kq = k >> 3, j = k & 7;
        int colb = part * 4;
        Bs[(kq * 128 + colb + 0) * 8 + j] = f2bf(v4.x);
        Bs[(kq * 128 + colb + 1) * 8 + j] = f2bf(v4.y);
        Bs[(kq * 128 + colb + 2) * 8 + j] = f2bf(v4.z);
        Bs[(kq * 128 + colb + 3) * 8 + j] = f2bf(v4.w);
    }

    f32x4 acc[4][4];
    #pragma unroll
    for (int rt = 0; rt < 4; ++rt)
        #pragma unroll
        for (int ct = 0; ct < 4; ++ct)
            acc[rt][ct] = f32x4{0.f, 0.f, 0.f, 0.f};

    for (int kt = 0; kt < 8; ++kt) {
        __syncthreads();
        // stage A tile 128 x 32 (fp32 -> bf16)
        #pragma unroll
        for (int s = 0; s < 4; ++s) {
            int c = tid + 256 * s;       // 0..1023
            int row = c >> 3, part = c & 7;
            const float4 v4 = *(const float4*)(x + (size_t)(m0 + row) * 256 + kt * 32 + part * 4);
            u16x4 h;
            h[0] = f2bf(v4.x); h[1] = f2bf(v4.y); h[2] = f2bf(v4.z); h[3] = f2bf(v4.w);
            *(u16x4*)&As[(((part >> 1) * 128 + row) * 8) + (part & 1) * 4] = h;
        }
        __syncthreads();

        bf16x8 af[4], bfr[4];
        #pragma unroll
        for (int rt = 0; rt < 4; ++rt)
            af[rt] = *(const bf16x8*)&As[(quad * 128 + wr + rt * 16 + m) * 8];
        #pragma unroll
        for (int ct = 0; ct < 4; ++ct)
            bfr[ct] = *(const bf16x8*)&Bs[((kt * 4 + quad) * 128 + wc + ct * 16 + m) * 8];
        #pragma unroll
        for (int rt = 0; rt < 4; ++rt)
            #pragma unroll
            for (int ct = 0; ct < 4; ++ct)
                acc[rt][ct] = __builtin_amdgcn_mfma_f32_16x16x32_bf16(
                    af[rt], bfr[ct], acc[rt][ct], 0, 0, 0);
    }

    const float scale = (nb < 2) ? 0.0625f : 1.0f;   // fold 1/sqrt(d) into q
    u16* buf = (nb < 2) ? qb : ((nb < 4) ? kb : vb);
    const int colshift = n0 - (nb >> 1) * 256;        // col offset inside q/k/v buffer

    #pragma unroll
    for (int rt = 0; rt < 4; ++rt) {
        #pragma unroll
        for (int ct = 0; ct < 4; ++ct) {
            int coll = wc + ct * 16 + m;              // col within 128-panel
            float bv = bias[n0 + coll];
            #pragma unroll
            for (int r = 0; r < 4; ++r) {
                int row = m0 + wr + rt * 16 + quad * 4 + r;
                float v = (acc[rt][ct][r] + bv) * scale;
                buf[(size_t)row * 256 + colshift + coll] = f2bf(v);
            }
        }
    }
}

// ---------------------------------------------------------------------------
// Windowed flash-retention: out[i] = sum_{j<=i, i-j<~W} (q_i.k_j) a^(i-j) v_j
// grid (64, 8), block 256. BM=64 (4 waves x 16 rows), BK=32, D=256, W=1024.
// ---------------------------------------------------------------------------
#define KS_STRIDE 264   // 528B rows: 16B aligned, ~2-way banks
#define VT_STRIDE 56    // 112B rows: 16B aligned
#define PS_STRIDE 56

__global__ __launch_bounds__(256, 2) void attn_kernel(
        const u16* __restrict__ qb, const u16* __restrict__ kb,
        const u16* __restrict__ vb, float* __restrict__ out)
{
    __shared__ __align__(16) u16 Ks[32 * KS_STRIDE];   // [key][d]
    __shared__ __align__(16) u16 Vt[256 * VT_STRIDE];  // [d][key]
    __shared__ __align__(16) u16 Ps[4 * 16 * PS_STRIDE]; // per-wave P tile [qrow][key]

    const int tid = threadIdx.x, lane = tid & 63, w = tid >> 6;
    const int b = blockIdx.y;
    const int m0 = blockIdx.x * 64;
    const int qrow0 = m0 + w * 16;
    const int m = lane & 15, quad = lane >> 4;
    const int rowbase = b * 4096;

    // q fragments for this wave's 16 rows, all of D=256 (A-layout)
    bf16x8 qf[8];
    #pragma unroll
    for (int k8 = 0; k8 < 8; ++k8)
        qf[k8] = *(const bf16x8*)(qb + (size_t)(rowbase + qrow0 + m) * 256 + k8 * 32 + quad * 8);

    f32x4 acc[16];
    #pragma unroll
    for (int dt = 0; dt < 16; ++dt) acc[dt] = f32x4{0.f, 0.f, 0.f, 0.f};

    int t0 = (m0 - 1024) >> 5; if (t0 < 0) t0 = 0;
    const int t1 = ((m0 + 64) >> 5) - 1;

    for (int t = t0; t <= t1; ++t) {
        const int j0 = t * 32;
        __syncthreads();   // previous iter's LDS reads done before restage

        // stage K tile [32 keys][256 d], row-major
        #pragma unroll
        for (int s = 0; s < 4; ++s) {
            int c = tid + 256 * s;        // 0..1023
            int row = c >> 5, part = c & 31;
            *(uint4*)&Ks[row * KS_STRIDE + part * 8] =
                *(const uint4*)(kb + (size_t)(rowbase + j0 + row) * 256 + part * 8);
        }
        // stage V tile transposed: Vt[d][key]
        #pragma unroll
        for (int s = 0; s < 2; ++s) {
            int it = tid + 256 * s;       // 0..511
            int rp = it & 15, cc = it >> 4;
            int r = rp * 2, c0 = cc * 8;
            u16x8 va = *(const u16x8*)(vb + (size_t)(rowbase + j0 + r) * 256 + c0);
            u16x8 vc = *(const u16x8*)(vb + (size_t)(rowbase + j0 + r + 1) * 256 + c0);
            #pragma unroll
            for (int e = 0; e < 8; ++e) {
                u32 val = (u32)va[e] | ((u32)vc[e] << 16);
                *(u32*)&Vt[(c0 + e) * VT_STRIDE + r] = val;
            }
        }
        __syncthreads();

        // S = q . k^T  (two 16x16 key-halves)
        f32x4 s0 = f32x4{0.f, 0.f, 0.f, 0.f};
        f32x4 s1 = f32x4{0.f, 0.f, 0.f, 0.f};
        #pragma unroll
        for (int k8 = 0; k8 < 8; ++k8) {
            bf16x8 b0 = *(const bf16x8*)&Ks[m * KS_STRIDE + k8 * 32 + quad * 8];
            s0 = __builtin_amdgcn_mfma_f32_16x16x32_bf16(qf[k8], b0, s0, 0, 0, 0);
        }
        #pragma unroll
        for (int k8 = 0; k8 < 8; ++k8) {
            bf16x8 b1 = *(const bf16x8*)&Ks[(16 + m) * KS_STRIDE + k8 * 32 + quad * 8];
            s1 = __builtin_amdgcn_mfma_f32_16x16x32_bf16(qf[k8], b1, s1, 0, 0, 0);
        }

        // decay mask, cast to bf16, write P to per-wave LDS (C-layout -> A-layout)
        #pragma unroll
        for (int r = 0; r < 4; ++r) {
            int i = qrow0 + quad * 4 + r;
            {
                int d = i - (j0 + m);
                float wgt = (d >= 0) ? __builtin_amdgcn_exp2f((float)d * L2ALPHA) : 0.0f;
                Ps[w * 16 * PS_STRIDE + (quad * 4 + r) * PS_STRIDE + m] = f2bf(s0[r] * wgt);
            }
            {
                int d = i - (j0 + 16 + m);
                float wgt = (d >= 0) ? __builtin_amdgcn_exp2f((float)d * L2ALPHA) : 0.0f;
                Ps[w * 16 * PS_STRIDE + (quad * 4 + r) * PS_STRIDE + 16 + m] = f2bf(s1[r] * wgt);
            }
        }
        asm volatile("s_waitcnt lgkmcnt(0)" ::: "memory");

        // O += P @ V
        bf16x8 pa = *(const bf16x8*)&Ps[w * 16 * PS_STRIDE + m * PS_STRIDE + quad * 8];
        #pragma unroll
        for (int dt = 0; dt < 16; ++dt) {
            bf16x8 vf = *(const bf16x8*)&Vt[(dt * 16 + m) * VT_STRIDE + quad * 8];
            acc[dt] = __builtin_amdgcn_mfma_f32_16x16x32_bf16(pa, vf, acc[dt], 0, 0, 0);
        }
    }

    #pragma unroll
    for (int dt = 0; dt < 16; ++dt)
        #pragma unroll
        for (int r = 0; r < 4; ++r)
            out[(size_t)(rowbase + qrow0 + quad * 4 + r) * 256 + dt * 16 + m] = acc[dt][r];
}

// ---------------------------------------------------------------------------
extern "C" void kernel_launch(void* const* d_in, const int* in_sizes, int n_in,
                              void* d_out, int out_size, void* d_ws, size_t ws_size,
                              hipStream_t stream) {
    (void)in_sizes; (void)n_in; (void)out_size; (void)ws_size;
    const float* x    = (const float*)d_in[0];
    const float* Wq   = (const float*)d_in[1];
    const float* bias = (const float*)d_in[2];
    float* outp = (float*)d_out;

    const size_t per = (size_t)8 * 4096 * 256;   // 8,388,608 elements per buffer
    u16* qb = (u16*)d_ws;
    u16* kb = qb + per;
    u16* vb = kb + per;

    proj_kernel<<<dim3(6, 256), 256, 0, stream>>>(x, Wq, bias, qb, kb, vb);
    attn_kernel<<<dim3(64, 8), 256, 0, stream>>>(qb, kb, vb, outp);
}

// Round 3
// 208.520 us; speedup vs baseline: 1.0746x; 1.0746x over previous
//
#include <hip/hip_runtime.h>

typedef __bf16 bf16x8 __attribute__((ext_vector_type(8)));
typedef float f32x4 __attribute__((ext_vector_type(4)));
typedef unsigned short u16;
typedef unsigned int u32;
typedef u16 u16x4 __attribute__((ext_vector_type(4)));

#define L2ALPHA (-0.014499569f)   // log2(0.99)

static __device__ __forceinline__ u16 f2bf(float f) {
    u32 u = __builtin_bit_cast(u32, f);
    return (u16)((u + 0x7FFFu + ((u >> 16) & 1u)) >> 16);
}

// async global->LDS, 16B per lane, dest must be wave-uniform-base + lane*16
static __device__ __forceinline__ void gl2lds16(const void* g, void* l) {
    __builtin_amdgcn_global_load_lds(
        (const __attribute__((address_space(1))) u32*)g,
        (__attribute__((address_space(3))) u32*)l, 16, 0, 0);
}

// ---------------------------------------------------------------------------
// Projection: qkv = x @ Wqkv + bqkv -> q (x1/16, [row][d]), K/V fragment-order.
// grid 384 = 6 nb-panels x 64 chunks; each block stages its W panel ONCE in
// LDS (fp32->bf16, fragment order) and computes 4 m-tiles of 128 rows.
// XCD swizzle: the 6 nb-blocks of one chunk share l%8 -> same XCD (x L2 reuse).
// ---------------------------------------------------------------------------
__global__ __launch_bounds__(256, 2) void proj_kernel(
        const float* __restrict__ x, const float* __restrict__ Wq,
        const float* __restrict__ bias,
        u16* __restrict__ qb, u16* __restrict__ kb, u16* __restrict__ vb)
{
    __shared__ __align__(16) u16 Bs[32 * 128 * 8];   // 64 KB: [k8][col][e]
    __shared__ __align__(16) u16 As[4 * 128 * 8];    // 8 KB

    const int tid = threadIdx.x, lane = tid & 63, w = tid >> 6;
    const int l = blockIdx.x;                 // 0..383
    const int nb = l >> 6;                    // 0..5
    const int chunk = ((l >> 3) & 7) * 8 + (l & 7);   // 0..63
    const int n0 = nb * 128;
    const int wr = (w & 1) * 64, wc = (w >> 1) * 64;
    const int m = lane & 15, quad = lane >> 4;

    // ---- stage W panel (256 x 128 fp32 -> bf16 fragment order), once ----
    {
        const int col = tid & 127;
        const int khalf = tid >> 7;           // 0..1
        #pragma unroll
        for (int s = 0; s < 32; ++s) {
            int k0 = (khalf + 2 * s) * 4;     // 0..252, step 4
            u16x4 h;
            #pragma unroll
            for (int i = 0; i < 4; ++i)
                h[i] = f2bf(Wq[(k0 + i) * 768 + n0 + col]);
            *(u16x4*)&Bs[((k0 >> 3) * 128 + col) * 8 + (k0 & 7)] = h;
        }
    }

    for (int it = 0; it < 4; ++it) {
        const int m0 = (chunk * 4 + it) * 128;

        f32x4 acc[4][4];
        #pragma unroll
        for (int rt = 0; rt < 4; ++rt)
            #pragma unroll
            for (int ct = 0; ct < 4; ++ct)
                acc[rt][ct] = f32x4{0.f, 0.f, 0.f, 0.f};

        for (int kt = 0; kt < 8; ++kt) {
            __syncthreads();   // it=0,kt=0: W-stage done; else: As reads done
            #pragma unroll
            for (int s = 0; s < 4; ++s) {
                int c = tid + 256 * s;
                int row = c >> 3, part = c & 7;
                const float4 v4 = *(const float4*)(x + (size_t)(m0 + row) * 256 + kt * 32 + part * 4);
                u16x4 h;
                h[0] = f2bf(v4.x); h[1] = f2bf(v4.y); h[2] = f2bf(v4.z); h[3] = f2bf(v4.w);
                *(u16x4*)&As[((part >> 1) * 128 + row) * 8 + (part & 1) * 4] = h;
            }
            __syncthreads();

            bf16x8 af[4], bfr[4];
            #pragma unroll
            for (int rt = 0; rt < 4; ++rt)
                af[rt] = *(const bf16x8*)&As[(quad * 128 + wr + rt * 16 + m) * 8];
            #pragma unroll
            for (int ct = 0; ct < 4; ++ct)
                bfr[ct] = *(const bf16x8*)&Bs[((kt * 4 + quad) * 128 + wc + ct * 16 + m) * 8];
            #pragma unroll
            for (int rt = 0; rt < 4; ++rt)
                #pragma unroll
                for (int ct = 0; ct < 4; ++ct)
                    acc[rt][ct] = __builtin_amdgcn_mfma_f32_16x16x32_bf16(
                        af[rt], bfr[ct], acc[rt][ct], 0, 0, 0);
        }

        const int b = m0 >> 12;
        const int jbase = (m0 & 4095) + wr;
        const int d0 = (nb & 1) * 128;

        if (nb < 2) {
            // Q: [row][d] bf16, pre-scaled by 1/sqrt(256)
            #pragma unroll
            for (int rt = 0; rt < 4; ++rt)
                #pragma unroll
                for (int ct = 0; ct < 4; ++ct) {
                    int coll = wc + ct * 16 + m;
                    float bv = bias[d0 + coll];
                    #pragma unroll
                    for (int r = 0; r < 4; ++r) {
                        int row = m0 + wr + rt * 16 + quad * 4 + r;
                        qb[(size_t)row * 256 + d0 + coll] = f2bf((acc[rt][ct][r] + bv) * 0.0625f);
                    }
                }
        } else if (nb < 4) {
            // K fragment-order: [b][jt][h][k8][qk*16+mk][e], e=d&7
            #pragma unroll
            for (int rt = 0; rt < 4; ++rt)
                #pragma unroll
                for (int ct = 0; ct < 4; ++ct) {
                    int d = d0 + wc + ct * 16 + m;
                    float bv = bias[256 + d];
                    int k8 = d >> 5, qk = (d >> 3) & 3, e = d & 7;
                    #pragma unroll
                    for (int r = 0; r < 4; ++r) {
                        int j = jbase + rt * 16 + quad * 4 + r;
                        int jt = j >> 5, hh = (j >> 4) & 1, mk = j & 15;
                        kb[((((size_t)(b * 128 + jt) * 2 + hh) * 8 + k8) * 64 + qk * 16 + mk) * 8 + e]
                            = f2bf(acc[rt][ct][r] + bv);
                    }
                }
        } else {
            // V fragment-order: [b][jt][dt][qv*16+mv][e], e=j&7 -> u16x4 over r
            #pragma unroll
            for (int rt = 0; rt < 4; ++rt)
                #pragma unroll
                for (int ct = 0; ct < 4; ++ct) {
                    int d = d0 + wc + ct * 16 + m;
                    float bv = bias[512 + d];
                    int dt = d >> 4, mv = d & 15;
                    int j = jbase + rt * 16 + quad * 4;
                    int jt = j >> 5, qv = (j >> 3) & 3, e0 = j & 7;
                    u16x4 hv;
                    #pragma unroll
                    for (int r = 0; r < 4; ++r) hv[r] = f2bf(acc[rt][ct][r] + bv);
                    *(u16x4*)&vb[(((size_t)(b * 128 + jt) * 16 + dt) * 64 + qv * 16 + mv) * 8 + e0] = hv;
                }
        }
    }
}

// ---------------------------------------------------------------------------
// Windowed flash-retention, BM=128 (4 waves x 32 q-rows), BK=32, W=1024.
// K/V panels are fragment-order 16 KB -> linear async staging, double-buffered.
// grid 256 (1-D, batch = id%8 for XCD L2 locality), block 256.
// ---------------------------------------------------------------------------
__global__ __launch_bounds__(256, 1) void attn_kernel(
        const u16* __restrict__ qb, const u16* __restrict__ kb,
        const u16* __restrict__ vb, float* __restrict__ out)
{
    __shared__ __align__(16) u16 Kf[2][8192];      // 2 x 16 KB
    __shared__ __align__(16) u16 Vf[2][8192];      // 2 x 16 KB
    __shared__ __align__(16) u16 Ps[4 * 2 * 16 * 40];  // per-wave P, stride 40

    const int tid = threadIdx.x, lane = tid & 63, w = tid >> 6;
    const int l = blockIdx.x;
    const int b = l & 7;                  // XCD-affine batch
    const int m0 = (l >> 3) * 128;
    const int qrow0 = m0 + w * 32;
    const int m = lane & 15, quad = lane >> 4;
    const size_t rowbase = (size_t)b * 4096;

    // q fragments: 2 row-groups x full D=256 (A-layout), direct from global
    bf16x8 qf[2][8];
    #pragma unroll
    for (int rg = 0; rg < 2; ++rg)
        #pragma unroll
        for (int k8 = 0; k8 < 8; ++k8)
            qf[rg][k8] = *(const bf16x8*)(qb + (rowbase + qrow0 + rg * 16 + m) * 256 + k8 * 32 + quad * 8);

    f32x4 acc[2][16];
    #pragma unroll
    for (int rg = 0; rg < 2; ++rg)
        #pragma unroll
        for (int dt = 0; dt < 16; ++dt)
            acc[rg][dt] = f32x4{0.f, 0.f, 0.f, 0.f};

    int t0 = (m0 - 1024) >> 5; if (t0 < 0) t0 = 0;
    const int t1 = (m0 >> 5) + 3;

    // prefetch first panel into buffer 0
    {
        const u16* kp = kb + (size_t)(b * 128 + t0) * 8192;
        const u16* vp = vb + (size_t)(b * 128 + t0) * 8192;
        #pragma unroll
        for (int s = 0; s < 4; ++s) {
            int c = tid + 256 * s;
            gl2lds16(kp + (size_t)c * 8, &Kf[0][c * 8]);
            gl2lds16(vp + (size_t)c * 8, &Vf[0][c * 8]);
        }
    }

    int p = 0;
    for (int t = t0; t <= t1; ++t) {
        __syncthreads();   // drains async copy of buf p; all waves done with buf p^1
        if (t < t1) {
            const u16* kp = kb + (size_t)(b * 128 + t + 1) * 8192;
            const u16* vp = vb + (size_t)(b * 128 + t + 1) * 8192;
            #pragma unroll
            for (int s = 0; s < 4; ++s) {
                int c = tid + 256 * s;
                gl2lds16(kp + (size_t)c * 8, &Kf[p ^ 1][c * 8]);
                gl2lds16(vp + (size_t)c * 8, &Vf[p ^ 1][c * 8]);
            }
        }
        const int j0 = t * 32;

        // S = q.k^T : two 16-key halves x two row-groups, b-frag reused x2
        f32x4 s00{0.f,0.f,0.f,0.f}, s01{0.f,0.f,0.f,0.f};
        f32x4 s10{0.f,0.f,0.f,0.f}, s11{0.f,0.f,0.f,0.f};
        #pragma unroll
        for (int k8 = 0; k8 < 8; ++k8) {
            bf16x8 bf0 = *(const bf16x8*)&Kf[p][(k8 * 64 + lane) * 8];
            s00 = __builtin_amdgcn_mfma_f32_16x16x32_bf16(qf[0][k8], bf0, s00, 0, 0, 0);
            s01 = __builtin_amdgcn_mfma_f32_16x16x32_bf16(qf[1][k8], bf0, s01, 0, 0, 0);
        }
        #pragma unroll
        for (int k8 = 0; k8 < 8; ++k8) {
            bf16x8 bf1 = *(const bf16x8*)&Kf[p][((8 + k8) * 64 + lane) * 8];
            s10 = __builtin_amdgcn_mfma_f32_16x16x32_bf16(qf[0][k8], bf1, s10, 0, 0, 0);
            s11 = __builtin_amdgcn_mfma_f32_16x16x32_bf16(qf[1][k8], bf1, s11, 0, 0, 0);
        }

        // decay-mask, bf16-cast, C-layout -> A-layout via per-wave LDS
        #pragma unroll
        for (int rg = 0; rg < 2; ++rg) {
            f32x4 sh0 = rg ? s01 : s00;
            f32x4 sh1 = rg ? s11 : s10;
            #pragma unroll
            for (int r = 0; r < 4; ++r) {
                int i = qrow0 + rg * 16 + quad * 4 + r;
                int dd0 = i - (j0 + m);
                int dd1 = dd0 - 16;
                float w0 = (dd0 >= 0) ? __builtin_amdgcn_exp2f((float)dd0 * L2ALPHA) : 0.0f;
                float w1 = (dd1 >= 0) ? __builtin_amdgcn_exp2f((float)dd1 * L2ALPHA) : 0.0f;
                int rowb = ((w * 2 + rg) * 16 + quad * 4 + r) * 40;
                Ps[rowb + m]      = f2bf(sh0[r] * w0);
                Ps[rowb + 16 + m] = f2bf(sh1[r] * w1);
            }
        }
        asm volatile("s_waitcnt lgkmcnt(0)" ::: "memory");  // wave-local P visibility

        bf16x8 pa0 = *(const bf16x8*)&Ps[((w * 2 + 0) * 16 + m) * 40 + quad * 8];
        bf16x8 pa1 = *(const bf16x8*)&Ps[((w * 2 + 1) * 16 + m) * 40 + quad * 8];

        // O += P @ V : v-frag reused across both row-groups
        #pragma unroll
        for (int dt = 0; dt < 16; ++dt) {
            bf16x8 vf = *(const bf16x8*)&Vf[p][(dt * 64 + lane) * 8];
            acc[0][dt] = __builtin_amdgcn_mfma_f32_16x16x32_bf16(pa0, vf, acc[0][dt], 0, 0, 0);
            acc[1][dt] = __builtin_amdgcn_mfma_f32_16x16x32_bf16(pa1, vf, acc[1][dt], 0, 0, 0);
        }
        p ^= 1;
    }

    #pragma unroll
    for (int rg = 0; rg < 2; ++rg)
        #pragma unroll
        for (int dt = 0; dt < 16; ++dt)
            #pragma unroll
            for (int r = 0; r < 4; ++r)
                out[(rowbase + qrow0 + rg * 16 + quad * 4 + r) * 256 + dt * 16 + m] = acc[rg][dt][r];
}

// ---------------------------------------------------------------------------
extern "C" void kernel_launch(void* const* d_in, const int* in_sizes, int n_in,
                              void* d_out, int out_size, void* d_ws, size_t ws_size,
                              hipStream_t stream) {
    (void)in_sizes; (void)n_in; (void)out_size; (void)ws_size;
    const float* x    = (const float*)d_in[0];
    const float* Wq   = (const float*)d_in[1];
    const float* bias = (const float*)d_in[2];
    float* outp = (float*)d_out;

    const size_t per = (size_t)8 * 4096 * 256;   // elems per q/k/v buffer (48 MB total)
    u16* qb = (u16*)d_ws;
    u16* kb = qb + per;
    u16* vb = kb + per;

    proj_kernel<<<384, 256, 0, stream>>>(x, Wq, bias, qb, kb, vb);
    attn_kernel<<<256, 256, 0, stream>>>(qb, kb, vb, outp);
}

// Round 4
// 191.144 us; speedup vs baseline: 1.1723x; 1.0909x over previous
//
#include <hip/hip_runtime.h>

typedef __bf16 bf16x8 __attribute__((ext_vector_type(8)));
typedef float f32x4 __attribute__((ext_vector_type(4)));
typedef unsigned short u16;
typedef unsigned int u32;
typedef u16 u16x4 __attribute__((ext_vector_type(4)));

#define L2ALPHA (-0.014499569f)   // log2(0.99)

static __device__ __forceinline__ u16 f2bf(float f) {
    u32 u = __builtin_bit_cast(u32, f);
    return (u16)((u + 0x7FFFu + ((u >> 16) & 1u)) >> 16);
}

// async global->LDS, 16B per lane, dest must be wave-uniform-base + lane*16
static __device__ __forceinline__ void gl2lds16(const void* g, void* l) {
    __builtin_amdgcn_global_load_lds(
        (const __attribute__((address_space(1))) u32*)g,
        (__attribute__((address_space(3))) u32*)l, 16, 0, 0);
}

// ---------------------------------------------------------------------------
// Projection (unchanged from R3): qkv = x @ Wqkv + bqkv.
// grid 384 = 6 nb-panels x 64 chunks; W panel staged once, 4 m-tiles/block.
// ---------------------------------------------------------------------------
__global__ __launch_bounds__(256, 2) void proj_kernel(
        const float* __restrict__ x, const float* __restrict__ Wq,
        const float* __restrict__ bias,
        u16* __restrict__ qb, u16* __restrict__ kb, u16* __restrict__ vb)
{
    __shared__ __align__(16) u16 Bs[32 * 128 * 8];   // 64 KB: [k8][col][e]
    __shared__ __align__(16) u16 As[4 * 128 * 8];    // 8 KB

    const int tid = threadIdx.x, lane = tid & 63, w = tid >> 6;
    const int l = blockIdx.x;                 // 0..383
    const int nb = l >> 6;                    // 0..5
    const int chunk = ((l >> 3) & 7) * 8 + (l & 7);   // 0..63
    const int n0 = nb * 128;
    const int wr = (w & 1) * 64, wc = (w >> 1) * 64;
    const int m = lane & 15, quad = lane >> 4;

    {
        const int col = tid & 127;
        const int khalf = tid >> 7;
        #pragma unroll
        for (int s = 0; s < 32; ++s) {
            int k0 = (khalf + 2 * s) * 4;
            u16x4 h;
            #pragma unroll
            for (int i = 0; i < 4; ++i)
                h[i] = f2bf(Wq[(k0 + i) * 768 + n0 + col]);
            *(u16x4*)&Bs[((k0 >> 3) * 128 + col) * 8 + (k0 & 7)] = h;
        }
    }

    for (int it = 0; it < 4; ++it) {
        const int m0 = (chunk * 4 + it) * 128;

        f32x4 acc[4][4];
        #pragma unroll
        for (int rt = 0; rt < 4; ++rt)
            #pragma unroll
            for (int ct = 0; ct < 4; ++ct)
                acc[rt][ct] = f32x4{0.f, 0.f, 0.f, 0.f};

        for (int kt = 0; kt < 8; ++kt) {
            __syncthreads();
            #pragma unroll
            for (int s = 0; s < 4; ++s) {
                int c = tid + 256 * s;
                int row = c >> 3, part = c & 7;
                const float4 v4 = *(const float4*)(x + (size_t)(m0 + row) * 256 + kt * 32 + part * 4);
                u16x4 h;
                h[0] = f2bf(v4.x); h[1] = f2bf(v4.y); h[2] = f2bf(v4.z); h[3] = f2bf(v4.w);
                *(u16x4*)&As[((part >> 1) * 128 + row) * 8 + (part & 1) * 4] = h;
            }
            __syncthreads();

            bf16x8 af[4], bfr[4];
            #pragma unroll
            for (int rt = 0; rt < 4; ++rt)
                af[rt] = *(const bf16x8*)&As[(quad * 128 + wr + rt * 16 + m) * 8];
            #pragma unroll
            for (int ct = 0; ct < 4; ++ct)
                bfr[ct] = *(const bf16x8*)&Bs[((kt * 4 + quad) * 128 + wc + ct * 16 + m) * 8];
            #pragma unroll
            for (int rt = 0; rt < 4; ++rt)
                #pragma unroll
                for (int ct = 0; ct < 4; ++ct)
                    acc[rt][ct] = __builtin_amdgcn_mfma_f32_16x16x32_bf16(
                        af[rt], bfr[ct], acc[rt][ct], 0, 0, 0);
        }

        const int b = m0 >> 12;
        const int jbase = (m0 & 4095) + wr;
        const int d0 = (nb & 1) * 128;

        if (nb < 2) {
            #pragma unroll
            for (int rt = 0; rt < 4; ++rt)
                #pragma unroll
                for (int ct = 0; ct < 4; ++ct) {
                    int coll = wc + ct * 16 + m;
                    float bv = bias[d0 + coll];
                    #pragma unroll
                    for (int r = 0; r < 4; ++r) {
                        int row = m0 + wr + rt * 16 + quad * 4 + r;
                        qb[(size_t)row * 256 + d0 + coll] = f2bf((acc[rt][ct][r] + bv) * 0.0625f);
                    }
                }
        } else if (nb < 4) {
            #pragma unroll
            for (int rt = 0; rt < 4; ++rt)
                #pragma unroll
                for (int ct = 0; ct < 4; ++ct) {
                    int d = d0 + wc + ct * 16 + m;
                    float bv = bias[256 + d];
                    int k8 = d >> 5, qk = (d >> 3) & 3, e = d & 7;
                    #pragma unroll
                    for (int r = 0; r < 4; ++r) {
                        int j = jbase + rt * 16 + quad * 4 + r;
                        int jt = j >> 5, hh = (j >> 4) & 1, mk = j & 15;
                        kb[((((size_t)(b * 128 + jt) * 2 + hh) * 8 + k8) * 64 + qk * 16 + mk) * 8 + e]
                            = f2bf(acc[rt][ct][r] + bv);
                    }
                }
        } else {
            #pragma unroll
            for (int rt = 0; rt < 4; ++rt)
                #pragma unroll
                for (int ct = 0; ct < 4; ++ct) {
                    int d = d0 + wc + ct * 16 + m;
                    float bv = bias[512 + d];
                    int dt = d >> 4, mv = d & 15;
                    int j = jbase + rt * 16 + quad * 4;
                    int jt = j >> 5, qv = (j >> 3) & 3, e0 = j & 7;
                    u16x4 hv;
                    #pragma unroll
                    for (int r = 0; r < 4; ++r) hv[r] = f2bf(acc[rt][ct][r] + bv);
                    *(u16x4*)&vb[(((size_t)(b * 128 + jt) * 16 + dt) * 64 + qv * 16 + mv) * 8 + e0] = hv;
                }
        }
    }
}

// ---------------------------------------------------------------------------
// Windowed flash-retention, 512 threads = 8 waves x 16 q-rows (BM=128).
// 2 waves/SIMD for latency hiding. Double-buffered fragment-order panels.
// grid 256 (batch = id%8 for XCD L2 locality).
// ---------------------------------------------------------------------------
__global__ __launch_bounds__(512, 2) void attn_kernel(
        const u16* __restrict__ qb, const u16* __restrict__ kb,
        const u16* __restrict__ vb, float* __restrict__ out)
{
    __shared__ __align__(16) u16 Kf[2][8192];      // 2 x 16 KB
    __shared__ __align__(16) u16 Vf[2][8192];      // 2 x 16 KB
    __shared__ __align__(16) u16 Ps[8 * 16 * 40];  // per-wave P, stride 40

    const int tid = threadIdx.x, lane = tid & 63, w = tid >> 6;   // w 0..7
    const int l = blockIdx.x;
    const int b = l & 7;                  // XCD-affine batch
    const int m0 = (l >> 3) * 128;
    const int qrow0 = m0 + w * 16;
    const int m = lane & 15, quad = lane >> 4;
    const size_t rowbase = (size_t)b * 4096;

    // q fragments: 16 rows x full D=256 (A-layout), direct from global
    bf16x8 qf[8];
    #pragma unroll
    for (int k8 = 0; k8 < 8; ++k8)
        qf[k8] = *(const bf16x8*)(qb + (rowbase + qrow0 + m) * 256 + k8 * 32 + quad * 8);

    f32x4 acc[16];
    #pragma unroll
    for (int dt = 0; dt < 16; ++dt) acc[dt] = f32x4{0.f, 0.f, 0.f, 0.f};

    int t0 = (m0 - 1024) >> 5; if (t0 < 0) t0 = 0;
    const int t1 = (m0 >> 5) + 3;

    // prefetch first panel into buffer 0 (512 threads -> 2 lines each)
    {
        const u16* kp = kb + (size_t)(b * 128 + t0) * 8192;
        const u16* vp = vb + (size_t)(b * 128 + t0) * 8192;
        #pragma unroll
        for (int s = 0; s < 2; ++s) {
            int c = tid + 512 * s;
            gl2lds16(kp + (size_t)c * 8, &Kf[0][c * 8]);
            gl2lds16(vp + (size_t)c * 8, &Vf[0][c * 8]);
        }
    }

    int p = 0;
    for (int t = t0; t <= t1; ++t) {
        __syncthreads();   // drains async copy of buf p; all waves done with buf p^1
        if (t < t1) {
            const u16* kp = kb + (size_t)(b * 128 + t + 1) * 8192;
            const u16* vp = vb + (size_t)(b * 128 + t + 1) * 8192;
            #pragma unroll
            for (int s = 0; s < 2; ++s) {
                int c = tid + 512 * s;
                gl2lds16(kp + (size_t)c * 8, &Kf[p ^ 1][c * 8]);
                gl2lds16(vp + (size_t)c * 8, &Vf[p ^ 1][c * 8]);
            }
        }
        const int j0 = t * 32;

        // wave-uniform skip: tile entirely after this wave's rows, or entirely
        // beyond the decay window (weight < 1e-7) -> barriers only
        if (j0 <= qrow0 + 15 && j0 + 1055 >= qrow0) {
            // S = q.k^T : two 16-key halves
            f32x4 s0{0.f,0.f,0.f,0.f}, s1{0.f,0.f,0.f,0.f};
            #pragma unroll
            for (int k8 = 0; k8 < 8; ++k8) {
                bf16x8 bf0 = *(const bf16x8*)&Kf[p][(k8 * 64 + lane) * 8];
                s0 = __builtin_amdgcn_mfma_f32_16x16x32_bf16(qf[k8], bf0, s0, 0, 0, 0);
            }
            #pragma unroll
            for (int k8 = 0; k8 < 8; ++k8) {
                bf16x8 bf1 = *(const bf16x8*)&Kf[p][((8 + k8) * 64 + lane) * 8];
                s1 = __builtin_amdgcn_mfma_f32_16x16x32_bf16(qf[k8], bf1, s1, 0, 0, 0);
            }

            // decay-mask, bf16-cast, C-layout -> A-layout via per-wave LDS
            #pragma unroll
            for (int r = 0; r < 4; ++r) {
                int i = qrow0 + quad * 4 + r;
                int dd0 = i - (j0 + m);
                int dd1 = dd0 - 16;
                float w0 = (dd0 >= 0) ? __builtin_amdgcn_exp2f((float)dd0 * L2ALPHA) : 0.0f;
                float w1 = (dd1 >= 0) ? __builtin_amdgcn_exp2f((float)dd1 * L2ALPHA) : 0.0f;
                int rowb = (w * 16 + quad * 4 + r) * 40;
                Ps[rowb + m]      = f2bf(s0[r] * w0);
                Ps[rowb + 16 + m] = f2bf(s1[r] * w1);
            }
            asm volatile("s_waitcnt lgkmcnt(0)" ::: "memory");  // wave-local P visibility

            bf16x8 pa = *(const bf16x8*)&Ps[(w * 16 + m) * 40 + quad * 8];

            // O += P @ V
            #pragma unroll
            for (int dt = 0; dt < 16; ++dt) {
                bf16x8 vf = *(const bf16x8*)&Vf[p][(dt * 64 + lane) * 8];
                acc[dt] = __builtin_amdgcn_mfma_f32_16x16x32_bf16(pa, vf, acc[dt], 0, 0, 0);
            }
        }
        p ^= 1;
    }

    #pragma unroll
    for (int dt = 0; dt < 16; ++dt)
        #pragma unroll
        for (int r = 0; r < 4; ++r)
            out[(rowbase + qrow0 + quad * 4 + r) * 256 + dt * 16 + m] = acc[dt][r];
}

// ---------------------------------------------------------------------------
extern "C" void kernel_launch(void* const* d_in, const int* in_sizes, int n_in,
                              void* d_out, int out_size, void* d_ws, size_t ws_size,
                              hipStream_t stream) {
    (void)in_sizes; (void)n_in; (void)out_size; (void)ws_size;
    const float* x    = (const float*)d_in[0];
    const float* Wq   = (const float*)d_in[1];
    const float* bias = (const float*)d_in[2];
    float* outp = (float*)d_out;

    const size_t per = (size_t)8 * 4096 * 256;   // elems per q/k/v buffer (48 MB total)
    u16* qb = (u16*)d_ws;
    u16* kb = qb + per;
    u16* vb = kb + per;

    proj_kernel<<<384, 256, 0, stream>>>(x, Wq, bias, qb, kb, vb);
    attn_kernel<<<256, 512, 0, stream>>>(qb, kb, vb, outp);
}